// Round 3
// baseline (27173.505 us; speedup 1.0000x reference)
//
#include <hip/hip_runtime.h>
#include <hip/hip_cooperative_groups.h>
#include <math.h>
#include <stdint.h>

namespace cg = cooperative_groups;

#define BB   2048
#define TT   100
#define DD   128
#define HH   256
#define NEGF -1.0e9f

typedef __attribute__((ext_vector_type(8))) short short8_t;   // 8 bf16 = 4 VGPR
typedef __attribute__((ext_vector_type(4))) float f32x4;

#define MFMA16(a,b,c) __builtin_amdgcn_mfma_f32_16x16x32_bf16((a),(b),(c),0,0,0)

__device__ __forceinline__ float sigmoidf_(float x){ return 1.0f/(1.0f+expf(-x)); }

// fast tanh for scores only: HW exp + HW rcp. |rel err| ~1e-7.
__device__ __forceinline__ float tanh_fast(float x){
  x = fminf(15.f, fmaxf(-15.f, x));
  const float e = __expf(x + x);
  return (e - 1.f) * __builtin_amdgcn_rcpf(e + 1.f);
}

__device__ __forceinline__ float b2f(unsigned u){ return __uint_as_float(u << 16); }

// 3-way bf16 split: x == h + m + l EXACTLY (24 mantissa bits covered).
__device__ __forceinline__ void bf16_split3(float x, unsigned short &h,
                                            unsigned short &m, unsigned short &l){
  const unsigned u = __float_as_uint(x);
  const unsigned r = u + 0x7FFFu + ((u >> 16) & 1u);
  h = (unsigned short)(r >> 16);
  const float rem = x - __uint_as_float(r & 0xFFFF0000u);
  const unsigned u2 = __float_as_uint(rem);
  const unsigned r2 = u2 + 0x7FFFu + ((u2 >> 16) & 1u);
  m = (unsigned short)(r2 >> 16);
  const float rem2 = rem - __uint_as_float(r2 & 0xFFFF0000u);
  l = (unsigned short)(__float_as_uint(rem2) >> 16);
}

__global__ __launch_bounds__(256) void k_split3(const float* __restrict__ src,
    unsigned short* __restrict__ hi, unsigned short* __restrict__ mi,
    unsigned short* __restrict__ lo, int n){
  const int i = blockIdx.x*256 + threadIdx.x;
  if(i < n){ unsigned short h,m,l; bf16_split3(src[i], h, m, l);
             hi[i]=h; mi[i]=m; lo[i]=l; }
}

__global__ __launch_bounds__(256) void k_zero_i32(int* __restrict__ p, int n){
  int i = blockIdx.x*256 + threadIdx.x;
  if(i < n) p[i] = 0;
}

// W2t[k][n] = W2[n][k]  (256x256 fp32)
__global__ __launch_bounds__(256) void k_transpose256(const float* __restrict__ in,
                                                      float* __restrict__ outp){
  const int k = blockIdx.x;
  const int n = threadIdx.x;
  outp[k*256 + n] = in[n*256 + k];
}

// 6-product bf16x6 accumulate, small terms first
#define MFMA_X6(aH,aM,aL,bH,bM,bL,acc)            \
  do{ acc = MFMA16(aM, bM, acc);                  \
      acc = MFMA16(aH, bL, acc);                  \
      acc = MFMA16(aL, bH, acc);                  \
      acc = MFMA16(aH, bM, acc);                  \
      acc = MFMA16(aM, bH, acc);                  \
      acc = MFMA16(aH, bH, acc); }while(0)

// ---- shared gates-tile machinery (block tile 64m x 32j x 4 strips; 256 thr) ----
struct GatesSmem {
  alignas(16) unsigned short AsH[64*40];
  alignas(16) unsigned short AsM[64*40];
  alignas(16) unsigned short AsL[64*40];
  alignas(16) unsigned short WsH[128*40];
  alignas(16) unsigned short WsM[128*40];
  alignas(16) unsigned short WsL[128*40];
};

__device__ __forceinline__ void stage_W(GatesSmem& sm,
    const unsigned short* __restrict__ WH, const unsigned short* __restrict__ WM,
    const unsigned short* __restrict__ WL, int ldw, int j0, int k0, int tid){
  #pragma unroll
  for(int half=0; half<3; half++){
    const unsigned short* __restrict__ Wg = (half==0)?WH:((half==1)?WM:WL);
    unsigned short* Ws = (half==0)?sm.WsH:((half==1)?sm.WsM:sm.WsL);
    #pragma unroll
    for(int it=0; it<2; it++){
      const int q  = it*256 + tid;
      const int cc = q >> 2;                  // 0..127 : strip*32 + j
      const int kq = (q & 3) << 3;            // 0,8,16,24
      const int n  = ((cc>>5)*HH) + j0 + (cc & 31);
      *(uint4*)&Ws[cc*40 + kq] = *(const uint4*)(Wg + (size_t)n*ldw + k0 + kq);
    }
  }
}

__device__ __forceinline__ void stage_A_presplit(GatesSmem& sm,
    const unsigned short* __restrict__ AH, const unsigned short* __restrict__ AM,
    const unsigned short* __restrict__ AL, int lda, int m0, int k0, int tid){
  const int r  = tid >> 2;                    // 0..63
  const int kq = (tid & 3) << 3;              // 0,8,16,24
  const size_t off = (size_t)(m0+r)*lda + k0 + kq;
  *(uint4*)&sm.AsH[r*40+kq] = *(const uint4*)(AH + off);
  *(uint4*)&sm.AsM[r*40+kq] = *(const uint4*)(AM + off);
  *(uint4*)&sm.AsL[r*40+kq] = *(const uint4*)(AL + off);
}

__device__ __forceinline__ void stage_A_f32(GatesSmem& sm,
    const float* __restrict__ A, size_t lda, int m0, int k0, int tid){
  #pragma unroll
  for(int it=0; it<2; it++){
    const int q  = it*256 + tid;              // 0..511
    const int r  = q >> 3;                    // 0..63
    const int kq = (q & 7) << 2;              // 0,4,...,28
    const float4 v = *(const float4*)(A + (size_t)(m0+r)*lda + k0 + kq);
    unsigned short h0,m0_,l0,h1,m1_,l1,h2,m2_,l2,h3,m3_,l3;
    bf16_split3(v.x,h0,m0_,l0); bf16_split3(v.y,h1,m1_,l1);
    bf16_split3(v.z,h2,m2_,l2); bf16_split3(v.w,h3,m3_,l3);
    *(ushort4*)&sm.AsH[r*40+kq] = make_ushort4(h0,h1,h2,h3);
    *(ushort4*)&sm.AsM[r*40+kq] = make_ushort4(m0_,m1_,m2_,m3_);
    *(ushort4*)&sm.AsL[r*40+kq] = make_ushort4(l0,l1,l2,l3);
  }
}

__device__ __forceinline__ void gates_compute(GatesSmem& sm, f32x4 (&acc)[2][4],
                                              int mh, int j16, int l15, int l4){
  short8_t aH[2], aM[2], aL[2];
  #pragma unroll
  for(int fm=0; fm<2; fm++){
    const int rr = mh*32 + fm*16 + l15;
    aH[fm] = *(const short8_t*)&sm.AsH[rr*40 + l4*8];
    aM[fm] = *(const short8_t*)&sm.AsM[rr*40 + l4*8];
    aL[fm] = *(const short8_t*)&sm.AsL[rr*40 + l4*8];
  }
  #pragma unroll
  for(int s4=0; s4<4; s4++){
    const int cc = s4*32 + j16 + l15;
    const short8_t bH = *(const short8_t*)&sm.WsH[cc*40 + l4*8];
    const short8_t bM = *(const short8_t*)&sm.WsM[cc*40 + l4*8];
    const short8_t bL = *(const short8_t*)&sm.WsL[cc*40 + l4*8];
    #pragma unroll
    for(int fm=0; fm<2; fm++){
      MFMA_X6(aH[fm],aM[fm],aL[fm], bH,bM,bL, acc[fm][s4]);
    }
  }
}

// ================= persistent encoder: 100 LSTM steps, grid.sync between =====
__global__ __launch_bounds__(256) void k_encoder(
    const float* __restrict__ targets,
    const unsigned short* __restrict__ WihH, const unsigned short* __restrict__ WihM,
    const unsigned short* __restrict__ WihL,
    const unsigned short* __restrict__ WhhH, const unsigned short* __restrict__ WhhM,
    const unsigned short* __restrict__ WhhL,
    const float* __restrict__ bih, const float* __restrict__ bhh,
    unsigned short* __restrict__ hAH, unsigned short* __restrict__ hAM,
    unsigned short* __restrict__ hAL,
    unsigned short* __restrict__ hBH, unsigned short* __restrict__ hBM,
    unsigned short* __restrict__ hBL,
    float* __restrict__ cbuf, float* __restrict__ blend1)
{
  cg::grid_group grid = cg::this_grid();
  __shared__ GatesSmem sm;
  const int tid  = threadIdx.x;
  const int lane = tid & 63;
  const int wv   = tid >> 6;
  const int l15  = lane & 15;
  const int l4   = lane >> 4;
  const int bid  = blockIdx.x;
  const int m0   = (bid >> 3) * 64;
  const int j0   = (bid & 7) * 32;
  const int mh   = wv & 1;
  const int j16  = (wv >> 1) * 16;

  const int j = j0 + j16 + l15;
  const float bi0 = bih[       j] + bhh[       j];
  const float bf0 = bih[  HH + j] + bhh[  HH + j];
  const float bg0 = bih[2*HH + j] + bhh[2*HH + j];
  const float bo0 = bih[3*HH + j] + bhh[3*HH + j];

  for(int t=0; t<TT; t++){
    f32x4 acc[2][4];
    #pragma unroll
    for(int a=0;a<2;a++)
      #pragma unroll
      for(int s=0;s<4;s++)
        #pragma unroll
        for(int e=0;e<4;e++) acc[a][s][e] = 0.f;

    // x phase: targets[:, t, :], inline split3
    for(int kt=0; kt<4; kt++){
      const int k0 = kt*32;
      __syncthreads();
      stage_A_f32(sm, targets + (size_t)t*DD, (size_t)TT*DD, m0, k0, tid);
      stage_W(sm, WihH, WihM, WihL, DD, j0, k0, tid);
      __syncthreads();
      gates_compute(sm, acc, mh, j16, l15, l4);
    }
    // h phase: pre-split h from previous step
    if(t > 0){
      const unsigned short* hH = (t&1) ? hAH : hBH;
      const unsigned short* hM = (t&1) ? hAM : hBM;
      const unsigned short* hL = (t&1) ? hAL : hBL;
      for(int kt=0; kt<8; kt++){
        const int k0 = kt*32;
        __syncthreads();
        stage_A_presplit(sm, hH, hM, hL, HH, m0, k0, tid);
        stage_W(sm, WhhH, WhhM, WhhL, HH, j0, k0, tid);
        __syncthreads();
        gates_compute(sm, acc, mh, j16, l15, l4);
      }
    }
    // epilogue: cell, write c (in place), split3 h, fp32 h into blend1 slot
    unsigned short* hoH = (t&1) ? hBH : hAH;
    unsigned short* hoM = (t&1) ? hBM : hAM;
    unsigned short* hoL = (t&1) ? hBL : hAL;
    #pragma unroll
    for(int fm=0; fm<2; fm++){
      #pragma unroll
      for(int r=0; r<4; r++){
        const int m = m0 + mh*32 + fm*16 + l4*4 + r;
        const size_t idx = (size_t)m*HH + j;
        const float iv = acc[fm][0][r] + bi0;
        const float fv = acc[fm][1][r] + bf0;
        const float gv = acc[fm][2][r] + bg0;
        const float ov = acc[fm][3][r] + bo0;
        const float cp = (t==0) ? 0.f : cbuf[idx];
        const float cn = sigmoidf_(fv)*cp + sigmoidf_(iv)*tanhf(gv);
        const float hn = sigmoidf_(ov)*tanhf(cn);
        cbuf[idx] = cn;
        unsigned short sh, sm_, sl;
        bf16_split3(hn, sh, sm_, sl);
        hoH[idx] = sh; hoM[idx] = sm_; hoL[idx] = sl;
        blend1[(size_t)m*(TT*256) + (size_t)t*256 + j] = hn;
      }
    }
    if(t < TT-1) grid.sync();
  }
}

// ================= persistent decoder: gates -> sync -> blend2+scores ========
__global__ __launch_bounds__(256) void k_decoder(
    const float* __restrict__ targets,
    const unsigned short* __restrict__ WihH, const unsigned short* __restrict__ WihM,
    const unsigned short* __restrict__ WihL,
    const unsigned short* __restrict__ WhhH, const unsigned short* __restrict__ WhhM,
    const unsigned short* __restrict__ WhhL,
    const float* __restrict__ bih, const float* __restrict__ bhh,
    const float* __restrict__ c0, float* __restrict__ cbuf,
    const unsigned short* __restrict__ hAH, const unsigned short* __restrict__ hAM,
    const unsigned short* __restrict__ hAL,
    unsigned short* __restrict__ hBH, unsigned short* __restrict__ hBM,
    unsigned short* __restrict__ hBL,
    unsigned short* __restrict__ decH, unsigned short* __restrict__ decM,
    unsigned short* __restrict__ decL,
    const float* __restrict__ W2t, const float* __restrict__ vt,
    const float* __restrict__ blend1,
    int* __restrict__ selected, float* __restrict__ outp)
{
  cg::grid_group grid = cg::this_grid();
  __shared__ GatesSmem sm;
  __shared__ float Hs[8][260];
  __shared__ float scs[8][104];
  const int tid  = threadIdx.x;
  const int lane = tid & 63;
  const int wv   = tid >> 6;
  const int l15  = lane & 15;
  const int l4   = lane >> 4;
  const int bid  = blockIdx.x;
  const int m0   = (bid >> 3) * 64;
  const int j0   = (bid & 7) * 32;
  const int mh   = wv & 1;
  const int j16  = (wv >> 1) * 16;
  const int r0b  = bid * 8;                     // phase-B rows

  const int j = j0 + j16 + l15;
  const float bi0 = bih[       j] + bhh[       j];
  const float bf0 = bih[  HH + j] + bhh[  HH + j];
  const float bg0 = bih[2*HH + j] + bhh[2*HH + j];
  const float bo0 = bih[3*HH + j] + bhh[3*HH + j];
  const float4 vv = *(const float4*)(vt + lane*4);

  for(int st=0; st<TT; st++){
    // ---------- phase A: gates + cell ----------
    f32x4 acc[2][4];
    #pragma unroll
    for(int a=0;a<2;a++)
      #pragma unroll
      for(int s=0;s<4;s++)
        #pragma unroll
        for(int e=0;e<4;e++) acc[a][s][e] = 0.f;

    if(st > 0){                                  // dec_in phase (zeros at st==0)
      for(int kt=0; kt<4; kt++){
        const int k0 = kt*32;
        __syncthreads();
        stage_A_presplit(sm, decH, decM, decL, DD, m0, k0, tid);
        stage_W(sm, WihH, WihM, WihL, DD, j0, k0, tid);
        __syncthreads();
        gates_compute(sm, acc, mh, j16, l15, l4);
      }
    }
    {                                            // h phase
      const unsigned short* hH = (st&1) ? hBH : hAH;
      const unsigned short* hM = (st&1) ? hBM : hAM;
      const unsigned short* hL = (st&1) ? hBL : hAL;
      for(int kt=0; kt<8; kt++){
        const int k0 = kt*32;
        __syncthreads();
        stage_A_presplit(sm, hH, hM, hL, HH, m0, k0, tid);
        stage_W(sm, WhhH, WhhM, WhhL, HH, j0, k0, tid);
        __syncthreads();
        gates_compute(sm, acc, mh, j16, l15, l4);
      }
    }
    {
      unsigned short* hoH = (st&1) ? (unsigned short*)hAH : hBH;
      unsigned short* hoM = (st&1) ? (unsigned short*)hAM : hBM;
      unsigned short* hoL = (st&1) ? (unsigned short*)hAL : hBL;
      const float* csrc = (st==0) ? c0 : cbuf;
      #pragma unroll
      for(int fm=0; fm<2; fm++){
        #pragma unroll
        for(int r=0; r<4; r++){
          const int m = m0 + mh*32 + fm*16 + l4*4 + r;
          const size_t idx = (size_t)m*HH + j;
          const float iv = acc[fm][0][r] + bi0;
          const float fv = acc[fm][1][r] + bf0;
          const float gv = acc[fm][2][r] + bg0;
          const float ov = acc[fm][3][r] + bo0;
          const float cp = csrc[idx];
          const float cn = sigmoidf_(fv)*cp + sigmoidf_(iv)*tanhf(gv);
          const float hn = sigmoidf_(ov)*tanhf(cn);
          cbuf[idx] = cn;
          unsigned short sh, sm_, sl;
          bf16_split3(hn, sh, sm_, sl);
          hoH[idx] = sh; hoM[idx] = sm_; hoL[idx] = sl;
        }
      }
    }
    grid.sync();

    // ---------- phase B: blend2 (VALU) + scores, fused ----------
    {
      // reconstruct this step's h rows (exact: h == H+M+L) into LDS
      const unsigned short* hH = (st&1) ? hAH : hBH;
      const unsigned short* hM = (st&1) ? hAM : hBM;
      const unsigned short* hL = (st&1) ? hAL : hBL;
      const int r  = tid >> 5;                   // 0..7
      const int kq = (tid & 31) << 3;            // 0..248
      const size_t off = (size_t)(r0b + r)*HH + kq;
      const uint4 uh = *(const uint4*)(hH + off);
      const uint4 um = *(const uint4*)(hM + off);
      const uint4 ul = *(const uint4*)(hL + off);
      #pragma unroll
      for(int e=0; e<4; e++){
        const unsigned wh = ((const unsigned*)&uh)[e];
        const unsigned wm = ((const unsigned*)&um)[e];
        const unsigned wl = ((const unsigned*)&ul)[e];
        Hs[r][kq + e*2 + 0] = b2f(wh & 0xffffu) + b2f(wm & 0xffffu) + b2f(wl & 0xffffu);
        Hs[r][kq + e*2 + 1] = b2f(wh >> 16)     + b2f(wm >> 16)     + b2f(wl >> 16);
      }
    }
    __syncthreads();

    // blend2: wave wv owns rows 2wv, 2wv+1; lane owns out cols lane*4..+3
    float bacc[2][4];
    #pragma unroll
    for(int r=0;r<2;r++)
      #pragma unroll
      for(int cG=0;cG<4;cG++) bacc[r][cG] = 0.f;
    {
      const int rA = wv*2, rB = wv*2 + 1;
      for(int kc=0; kc<64; kc++){
        const float4 ha = *(const float4*)&Hs[rA][kc*4];
        const float4 hb = *(const float4*)&Hs[rB][kc*4];
        const float haa[4] = {ha.x,ha.y,ha.z,ha.w};
        const float hbb[4] = {hb.x,hb.y,hb.z,hb.w};
        #pragma unroll
        for(int i=0;i<4;i++){
          const float4 w = *(const float4*)(W2t + (size_t)(kc*4+i)*HH + lane*4);
          bacc[0][0] = fmaf(haa[i], w.x, bacc[0][0]);
          bacc[0][1] = fmaf(haa[i], w.y, bacc[0][1]);
          bacc[0][2] = fmaf(haa[i], w.z, bacc[0][2]);
          bacc[0][3] = fmaf(haa[i], w.w, bacc[0][3]);
          bacc[1][0] = fmaf(hbb[i], w.x, bacc[1][0]);
          bacc[1][1] = fmaf(hbb[i], w.y, bacc[1][1]);
          bacc[1][2] = fmaf(hbb[i], w.z, bacc[1][2]);
          bacc[1][3] = fmaf(hbb[i], w.w, bacc[1][3]);
        }
      }
    }

    // scores for the wave's 2 rows (blend2 kept in registers)
    #pragma unroll
    for(int rr=0; rr<2; rr++){
      const int r = wv*2 + rr;
      const int brow = r0b + r;
      const float4 bb = make_float4(bacc[rr][0], bacc[rr][1], bacc[rr][2], bacc[rr][3]);
      const float* bl = blend1 + (size_t)brow * (TT*256);
      #pragma unroll 2
      for(int t=0; t<TT; t++){
        const float4 x = *(const float4*)(bl + t*256 + lane*4);
        float p;
        p = tanh_fast(x.x + bb.x) * vv.x;
        p = fmaf(tanh_fast(x.y + bb.y), vv.y, p);
        p = fmaf(tanh_fast(x.z + bb.z), vv.z, p);
        p = fmaf(tanh_fast(x.w + bb.w), vv.w, p);
        #pragma unroll
        for(int off=32; off>=1; off>>=1) p += __shfl_xor(p, off, 64);
        if(lane == 0) scs[r][t] = p;
      }
      const size_t selbase = (size_t)brow*TT;
      const float m1 = selected[selbase + lane] ? NEGF : scs[r][lane];
      float bestv = m1; int besti = lane;
      const int t2 = lane + 64;
      float m2 = NEGF;
      if(t2 < TT){
        m2 = selected[selbase + t2] ? NEGF : scs[r][t2];
        if(m2 > bestv){ bestv = m2; besti = t2; }
      }
      #pragma unroll
      for(int off=32; off>=1; off>>=1){
        const float ov = __shfl_xor(bestv, off, 64);
        const int   oi = __shfl_xor(besti, off, 64);
        if(ov > bestv || (ov == bestv && oi < besti)){ bestv = ov; besti = oi; }
      }
      float e = __expf(m1 - bestv);
      if(t2 < TT) e += __expf(m2 - bestv);
      #pragma unroll
      for(int off=32; off>=1; off>>=1) e += __shfl_xor(e, off, 64);

      outp[(size_t)brow*(TT*TT) + (size_t)st*TT + lane] = fmaxf(__expf(m1 - bestv)/e, 1e-9f);
      if(t2 < TT)
        outp[(size_t)brow*(TT*TT) + (size_t)st*TT + t2] = fmaxf(__expf(m2 - bestv)/e, 1e-9f);
      if(lane == 0) selected[selbase + besti] = 1;
      // gather next dec_in, pre-split
      #pragma unroll
      for(int dd=0; dd<2; dd++){
        const int d = lane + dd*64;
        const float xv = targets[((size_t)brow*TT + besti)*DD + d];
        unsigned short th, tm, tl;
        bf16_split3(xv, th, tm, tl);
        decH[(size_t)brow*DD + d] = th;
        decM[(size_t)brow*DD + d] = tm;
        decL[(size_t)brow*DD + d] = tl;
      }
    }
    if(st < TT-1) grid.sync();
  }
}

// In-place row transform: blend1_rows <- blend1_rows @ W1^T, bf16x6 MFMA.
__global__ __launch_bounds__(128) void k_blend1(
    float* __restrict__ blend1,
    const unsigned short* __restrict__ W1H, const unsigned short* __restrict__ W1M,
    const unsigned short* __restrict__ W1L)
{
  __shared__ alignas(16) unsigned short AsH[32*264], AsM[32*264], AsL[32*264];
  const int tid  = threadIdx.x;
  const int lane = tid & 63;
  const int wv   = tid >> 6;
  const int l15  = lane & 15;
  const int l4   = lane >> 4;
  const size_t r0 = (size_t)blockIdx.x * 32;

  #pragma unroll
  for(int it=0; it<16; it++){
    const int q  = it*128 + tid;                    // 0..2047
    const int r  = q >> 6;
    const int kq = (q & 63) << 2;
    const float4 v = *(const float4*)(blend1 + (r0+r)*256 + kq);
    unsigned short h0,m0_,l0,h1,m1_,l1,h2,m2_,l2,h3,m3_,l3;
    bf16_split3(v.x,h0,m0_,l0); bf16_split3(v.y,h1,m1_,l1);
    bf16_split3(v.z,h2,m2_,l2); bf16_split3(v.w,h3,m3_,l3);
    *(ushort4*)&AsH[r*264+kq] = make_ushort4(h0,h1,h2,h3);
    *(ushort4*)&AsM[r*264+kq] = make_ushort4(m0_,m1_,m2_,m3_);
    *(ushort4*)&AsL[r*264+kq] = make_ushort4(l0,l1,l2,l3);
  }
  __syncthreads();

  f32x4 acc[16];
  #pragma unroll
  for(int s=0;s<16;s++)
    #pragma unroll
    for(int e=0;e<4;e++) acc[s][e] = 0.f;

  const int rb = wv*16;
  for(int kt=0; kt<8; kt++){
    const int k0 = kt*32;
    const short8_t aH = *(const short8_t*)&AsH[(rb+l15)*264 + k0 + l4*8];
    const short8_t aM = *(const short8_t*)&AsM[(rb+l15)*264 + k0 + l4*8];
    const short8_t aL = *(const short8_t*)&AsL[(rb+l15)*264 + k0 + l4*8];
    #pragma unroll
    for(int fn=0; fn<16; fn++){
      const int n = fn*16 + l15;
      const short8_t bH = *(const short8_t*)(W1H + (size_t)n*256 + k0 + l4*8);
      const short8_t bM = *(const short8_t*)(W1M + (size_t)n*256 + k0 + l4*8);
      const short8_t bL = *(const short8_t*)(W1L + (size_t)n*256 + k0 + l4*8);
      MFMA_X6(aH,aM,aL, bH,bM,bL, acc[fn]);
    }
  }
  #pragma unroll
  for(int fn=0; fn<16; fn++)
    #pragma unroll
    for(int r=0; r<4; r++)
      blend1[(r0 + rb + l4*4 + r)*256 + fn*16 + l15] = acc[fn][r];
}

extern "C" void kernel_launch(void* const* d_in, const int* in_sizes, int n_in,
                              void* d_out, int out_size, void* d_ws, size_t ws_size,
                              hipStream_t stream)
{
  (void)in_sizes; (void)n_in; (void)out_size; (void)ws_size;
  const float* targets  = (const float*)d_in[0];
  const float* h0       = (const float*)d_in[1];
  const float* c0       = (const float*)d_in[2];
  const float* enc_w_ih = (const float*)d_in[3];
  const float* enc_w_hh = (const float*)d_in[4];
  const float* enc_b_ih = (const float*)d_in[5];
  const float* enc_b_hh = (const float*)d_in[6];
  const float* dec_w_ih = (const float*)d_in[7];
  const float* dec_w_hh = (const float*)d_in[8];
  const float* dec_b_ih = (const float*)d_in[9];
  const float* dec_b_hh = (const float*)d_in[10];
  const float* W1       = (const float*)d_in[11];
  const float* W2       = (const float*)d_in[12];
  const float* vt       = (const float*)d_in[13];
  float* outp = (float*)d_out;

  // ---- workspace carve-up (~224 MB) ----
  float* ws      = (float*)d_ws;
  float* blend1  = ws;                               // B*T*256
  float* cbuf    = blend1 + (size_t)BB*TT*256;       // B*H
  float* W2t     = cbuf + (size_t)BB*HH;             // 256*256
  int*   selected= (int*)(W2t + 256*256);            // B*T
  char* pc = (char*)(selected + (size_t)BB*TT);
  pc = (char*)(((uintptr_t)pc + 63) & ~(uintptr_t)63);
  unsigned short* q = (unsigned short*)pc;
  unsigned short* hsAH = q; q += (size_t)BB*HH;
  unsigned short* hsAM = q; q += (size_t)BB*HH;
  unsigned short* hsAL = q; q += (size_t)BB*HH;
  unsigned short* hsBH = q; q += (size_t)BB*HH;
  unsigned short* hsBM = q; q += (size_t)BB*HH;
  unsigned short* hsBL = q; q += (size_t)BB*HH;
  unsigned short* ewihH = q; q += (size_t)1024*128;
  unsigned short* ewihM = q; q += (size_t)1024*128;
  unsigned short* ewihL = q; q += (size_t)1024*128;
  unsigned short* ewhhH = q; q += (size_t)1024*256;
  unsigned short* ewhhM = q; q += (size_t)1024*256;
  unsigned short* ewhhL = q; q += (size_t)1024*256;
  unsigned short* dwihH = q; q += (size_t)1024*128;
  unsigned short* dwihM = q; q += (size_t)1024*128;
  unsigned short* dwihL = q; q += (size_t)1024*128;
  unsigned short* dwhhH = q; q += (size_t)1024*256;
  unsigned short* dwhhM = q; q += (size_t)1024*256;
  unsigned short* dwhhL = q; q += (size_t)1024*256;
  unsigned short* w1H   = q; q += (size_t)256*256;
  unsigned short* w1M   = q; q += (size_t)256*256;
  unsigned short* w1L   = q; q += (size_t)256*256;
  // dec_in splits alias the encoder-only ewih/ewhh region (encoder finishes first)
  unsigned short* decH = ewihH;
  unsigned short* decM = ewihH + (size_t)BB*DD;
  unsigned short* decL = ewihH + (size_t)2*BB*DD;

  // ---- prep ----
  k_split3<<<(1024*128+255)/256, 256, 0, stream>>>(enc_w_ih, ewihH, ewihM, ewihL, 1024*128);
  k_split3<<<(1024*256+255)/256, 256, 0, stream>>>(enc_w_hh, ewhhH, ewhhM, ewhhL, 1024*256);
  k_split3<<<(1024*128+255)/256, 256, 0, stream>>>(dec_w_ih, dwihH, dwihM, dwihL, 1024*128);
  k_split3<<<(1024*256+255)/256, 256, 0, stream>>>(dec_w_hh, dwhhH, dwhhM, dwhhL, 1024*256);
  k_split3<<<(256*256+255)/256,  256, 0, stream>>>(W1, w1H, w1M, w1L, 256*256);
  k_transpose256<<<256, 256, 0, stream>>>(W2, W2t);
  k_zero_i32<<<(BB*TT + 255)/256, 256, 0, stream>>>(selected, BB*TT);

  // ---- encoder (persistent cooperative) ----
  {
    void* args[] = {
      (void*)&targets,
      (void*)&ewihH, (void*)&ewihM, (void*)&ewihL,
      (void*)&ewhhH, (void*)&ewhhM, (void*)&ewhhL,
      (void*)&enc_b_ih, (void*)&enc_b_hh,
      (void*)&hsAH, (void*)&hsAM, (void*)&hsAL,
      (void*)&hsBH, (void*)&hsBM, (void*)&hsBL,
      (void*)&cbuf, (void*)&blend1
    };
    hipLaunchCooperativeKernel((void*)k_encoder, dim3(256), dim3(256), args, 0, stream);
  }

  // ---- blend1 = enc_states @ W1^T, in place ----
  k_blend1<<<BB*TT/32, 128, 0, stream>>>(blend1, w1H, w1M, w1L);

  // ---- h0 split into hsA (decoder step 0 reads hsA) ----
  k_split3<<<(BB*HH+255)/256, 256, 0, stream>>>(h0, hsAH, hsAM, hsAL, BB*HH);

  // ---- decoder (persistent cooperative) ----
  {
    void* args[] = {
      (void*)&targets,
      (void*)&dwihH, (void*)&dwihM, (void*)&dwihL,
      (void*)&dwhhH, (void*)&dwhhM, (void*)&dwhhL,
      (void*)&dec_b_ih, (void*)&dec_b_hh,
      (void*)&c0, (void*)&cbuf,
      (void*)&hsAH, (void*)&hsAM, (void*)&hsAL,
      (void*)&hsBH, (void*)&hsBM, (void*)&hsBL,
      (void*)&decH, (void*)&decM, (void*)&decL,
      (void*)&W2t, (void*)&vt,
      (void*)&blend1,
      (void*)&selected, (void*)&outp
    };
    hipLaunchCooperativeKernel((void*)k_decoder, dim3(256), dim3(256), args, 0, stream);
  }
}

// Round 4
// 15940.071 us; speedup vs baseline: 1.7047x; 1.7047x over previous
//
#include <hip/hip_runtime.h>
#include <math.h>
#include <stdint.h>

#define BB 2048
#define TT 100
#define DD 128
#define HH 256
#define NEGF -1.0e9f

#define NBLK 128          // blocks (one per 16 batch rows)
#define ROWS 16           // batch rows per block
#define NTHR 512          // 8 waves
#define KTOT 384          // 128 (x) + 256 (h)
#define NKF  12           // 384/32 k-fragments
#define ASTR 392          // shorts per A-LDS row (384 + 8 pad)

typedef __attribute__((ext_vector_type(8))) short short8_t;   // 8 bf16
typedef __attribute__((ext_vector_type(4))) float f32x4;

#define MFMA16(a,b,c) __builtin_amdgcn_mfma_f32_16x16x32_bf16((a),(b),(c),0,0,0)
// 6-product bf16x6 accumulate, small terms first (exact-split fp32 emulation)
#define MFMA_X6(aH,aM,aL,bH,bM,bL,acc)            \
  do{ acc = MFMA16(aM, bM, acc);                  \
      acc = MFMA16(aH, bL, acc);                  \
      acc = MFMA16(aL, bH, acc);                  \
      acc = MFMA16(aH, bM, acc);                  \
      acc = MFMA16(aM, bH, acc);                  \
      acc = MFMA16(aH, bH, acc); }while(0)

__device__ __forceinline__ float sigmoidf_(float x){ return 1.0f/(1.0f+expf(-x)); }

// fast tanh for scores only: HW exp + HW rcp. |rel err| ~1e-7.
__device__ __forceinline__ float tanh_fast(float x){
  x = fminf(15.f, fmaxf(-15.f, x));
  const float e = __expf(x + x);
  return (e - 1.f) * __builtin_amdgcn_rcpf(e + 1.f);
}

// 3-way bf16 split: x == h + m + l EXACTLY (24 mantissa bits covered).
__device__ __forceinline__ void bf16_split3(float x, unsigned short &h,
                                            unsigned short &m, unsigned short &l){
  const unsigned u = __float_as_uint(x);
  const unsigned r = u + 0x7FFFu + ((u >> 16) & 1u);
  h = (unsigned short)(r >> 16);
  const float rem = x - __uint_as_float(r & 0xFFFF0000u);
  const unsigned u2 = __float_as_uint(rem);
  const unsigned r2 = u2 + 0x7FFFu + ((u2 >> 16) & 1u);
  m = (unsigned short)(r2 >> 16);
  const float rem2 = rem - __uint_as_float(r2 & 0xFFFF0000u);
  l = (unsigned short)(__float_as_uint(rem2) >> 16);
}

__global__ __launch_bounds__(256) void k_split3(const float* __restrict__ src,
    unsigned short* __restrict__ hi, unsigned short* __restrict__ mi,
    unsigned short* __restrict__ lo, int n){
  const int i = blockIdx.x*256 + threadIdx.x;
  if(i < n){ unsigned short h,m,l; bf16_split3(src[i], h, m, l);
             hi[i]=h; mi[i]=m; lo[i]=l; }
}

// W2t[k][n] = W2[n][k]
__global__ __launch_bounds__(256) void k_transpose256(const float* __restrict__ in,
                                                      float* __restrict__ outp){
  const int k = blockIdx.x;
  const int n = threadIdx.x;
  outp[k*256 + n] = in[n*256 + k];
}

// Pack {w_ih[1024][128], w_hh[1024][256]} -> fragment-ordered bf16x3:
// element i = ((f*NKF + kf)*64 + lane)*8 + e  maps to  n = f*16+(lane&15),
// k = kf*32 + (lane>>4)*8 + e.  B-frag load becomes one coalesced 16B/lane read.
__global__ __launch_bounds__(256) void k_packW(
    const float* __restrict__ w_ih, const float* __restrict__ w_hh,
    unsigned short* __restrict__ WfH, unsigned short* __restrict__ WfM,
    unsigned short* __restrict__ WfL)
{
  const int i = blockIdx.x*256 + threadIdx.x;
  if(i >= 1024*KTOT) return;
  const int f    = i / (NKF*64*8);
  const int r1   = i % (NKF*64*8);
  const int kf   = r1 >> 9;
  const int r2   = r1 & 511;
  const int lane = r2 >> 3;
  const int e    = r2 & 7;
  const int n = f*16 + (lane & 15);
  const int k = kf*32 + (lane >> 4)*8 + e;
  const float w = (k < DD) ? w_ih[(size_t)n*DD + k] : w_hh[(size_t)n*HH + (k-DD)];
  unsigned short h,m,l; bf16_split3(w,h,m,l);
  WfH[i]=h; WfM[i]=m; WfL[i]=l;
}

// swizzled A-LDS short-index: row stride ASTR shorts, XOR bit4 of byte offset by row&7 (T2)
__device__ __forceinline__ int swA(int row, int byteoff){
  return row*ASTR + (((byteoff) ^ ((row & 7) << 4)) >> 1);
}

// ============ persistent-block encoder: 16 batch rows, 100 steps in-block ====
__global__ __launch_bounds__(NTHR) void k_encoder(
    const float* __restrict__ targets,
    const unsigned short* __restrict__ WfH, const unsigned short* __restrict__ WfM,
    const unsigned short* __restrict__ WfL,
    const float* __restrict__ bih, const float* __restrict__ bhh,
    float* __restrict__ blend1)
{
  __shared__ unsigned short AsH[ROWS*ASTR], AsM[ROWS*ASTR], AsL[ROWS*ASTR];
  const int tid = threadIdx.x;
  const int lane = tid & 63;
  const int wv = tid >> 6;
  const int l15 = lane & 15, l4 = lane >> 4;
  const int b0 = blockIdx.x * ROWS;

  float bias[8];
  #pragma unroll
  for(int g=0; g<4; g++)
    #pragma unroll
    for(int c16=0; c16<2; c16++){
      const int n = g*256 + wv*32 + c16*16 + l15;
      bias[g*2+c16] = bih[n] + bhh[n];
    }
  float cst[2][4];
  #pragma unroll
  for(int a=0;a<2;a++)
    #pragma unroll
    for(int r=0;r<4;r++) cst[a][r] = 0.f;

  for(int i=tid; i<ROWS*ASTR; i+=NTHR){ AsH[i]=0; AsM[i]=0; AsL[i]=0; }

  const int srow = tid >> 5;                 // staging: row, 4 k-elems
  const int k4   = (tid & 31) * 4;
  const int sidx = swA(srow, k4*2);

  for(int t=0; t<TT; t++){
    __syncthreads();                         // init / prev epilogue done
    {                                        // stage x = targets[:, t, :] split3
      const float4 v = *(const float4*)(targets + ((size_t)(b0+srow)*TT + t)*DD + k4);
      unsigned short h0,m0_,l0,h1,m1_,l1,h2,m2_,l2,h3,m3_,l3;
      bf16_split3(v.x,h0,m0_,l0); bf16_split3(v.y,h1,m1_,l1);
      bf16_split3(v.z,h2,m2_,l2); bf16_split3(v.w,h3,m3_,l3);
      *(ushort4*)&AsH[sidx] = make_ushort4(h0,h1,h2,h3);
      *(ushort4*)&AsM[sidx] = make_ushort4(m0_,m1_,m2_,m3_);
      *(ushort4*)&AsL[sidx] = make_ushort4(l0,l1,l2,l3);
    }
    __syncthreads();
    f32x4 acc[8];
    #pragma unroll
    for(int ff=0; ff<8; ff++){
      acc[ff][0]=bias[ff]; acc[ff][1]=bias[ff]; acc[ff][2]=bias[ff]; acc[ff][3]=bias[ff];
    }
    for(int kf=0; kf<NKF; kf++){
      const int ao = swA(l15, kf*64 + l4*16);
      const short8_t aH = *(const short8_t*)&AsH[ao];
      const short8_t aM = *(const short8_t*)&AsM[ao];
      const short8_t aL = *(const short8_t*)&AsL[ao];
      #pragma unroll
      for(int g=0; g<4; g++)
        #pragma unroll
        for(int c16=0; c16<2; c16++){
          const int f = g*16 + wv*2 + c16;
          const size_t wo = ((size_t)(f*NKF + kf)*64 + lane)*8;
          const short8_t bH = *(const short8_t*)(WfH + wo);
          const short8_t bM = *(const short8_t*)(WfM + wo);
          const short8_t bL = *(const short8_t*)(WfL + wo);
          MFMA_X6(aH,aM,aL,bH,bM,bL, acc[g*2+c16]);
        }
    }
    __syncthreads();                         // MFMA reads done before h-region writes
    #pragma unroll
    for(int c16=0; c16<2; c16++){
      const int j = wv*32 + c16*16 + l15;
      #pragma unroll
      for(int r=0; r<4; r++){
        const int row = l4*4 + r;
        const float iv = acc[0+c16][r];
        const float fv = acc[2+c16][r];
        const float gv = acc[4+c16][r];
        const float ov = acc[6+c16][r];
        const float cn = sigmoidf_(fv)*cst[c16][r] + sigmoidf_(iv)*tanhf(gv);
        const float hn = sigmoidf_(ov)*tanhf(cn);
        cst[c16][r] = cn;
        unsigned short sh, sm_, sl;
        bf16_split3(hn, sh, sm_, sl);
        const int hi = swA(row, (128 + j)*2);
        AsH[hi] = sh; AsM[hi] = sm_; AsL[hi] = sl;
        blend1[((size_t)(b0+row)*TT + t)*256 + j] = hn;
      }
    }
  }
}

// ============ persistent-block decoder: gates+cell -> blend2 -> scores =======
__global__ __launch_bounds__(NTHR) void k_decoder(
    const float* __restrict__ targets,
    const unsigned short* __restrict__ WfH, const unsigned short* __restrict__ WfM,
    const unsigned short* __restrict__ WfL,
    const float* __restrict__ bih, const float* __restrict__ bhh,
    const float* __restrict__ h0, const float* __restrict__ c0,
    const float* __restrict__ W2t, const float* __restrict__ vt,
    const float* __restrict__ blend1,
    float* __restrict__ outp)
{
  __shared__ unsigned short AsH[ROWS*ASTR], AsM[ROWS*ASTR], AsL[ROWS*ASTR];
  __shared__ float hs[ROWS*264];
  __shared__ float b2s[ROWS*264];
  __shared__ float sc[ROWS][104];
  __shared__ float vts[256];
  __shared__ char selc[ROWS][104];
  const int tid = threadIdx.x;
  const int lane = tid & 63;
  const int wv = tid >> 6;
  const int l15 = lane & 15, l4 = lane >> 4;
  const int b0 = blockIdx.x * ROWS;

  float bias[8];
  #pragma unroll
  for(int g=0; g<4; g++)
    #pragma unroll
    for(int c16=0; c16<2; c16++){
      const int n = g*256 + wv*32 + c16*16 + l15;
      bias[g*2+c16] = bih[n] + bhh[n];
    }

  for(int i=tid; i<ROWS*ASTR; i+=NTHR){ AsH[i]=0; AsM[i]=0; AsL[i]=0; } // x=0 @ st0
  if(tid < 256) vts[tid] = vt[tid];
  for(int i=tid; i<ROWS*104; i+=NTHR) (&selc[0][0])[i] = 0;
  {                                          // h0 -> A h-region split3
    const int row = tid >> 5;
    const int k8  = (tid & 31) * 8;
    #pragma unroll
    for(int ii=0; ii<8; ii+=4){
      const float4 v = *(const float4*)(h0 + (size_t)(b0+row)*HH + k8 + ii);
      unsigned short h0_,m0_,l0,h1,m1_,l1,h2,m2_,l2,h3,m3_,l3;
      bf16_split3(v.x,h0_,m0_,l0); bf16_split3(v.y,h1,m1_,l1);
      bf16_split3(v.z,h2,m2_,l2); bf16_split3(v.w,h3,m3_,l3);
      const int idx = swA(row, (128 + k8 + ii)*2);
      *(ushort4*)&AsH[idx] = make_ushort4(h0_,h1,h2,h3);
      *(ushort4*)&AsM[idx] = make_ushort4(m0_,m1_,m2_,m3_);
      *(ushort4*)&AsL[idx] = make_ushort4(l0,l1,l2,l3);
    }
  }
  float cst[2][4];
  #pragma unroll
  for(int c16=0; c16<2; c16++)
    #pragma unroll
    for(int r=0; r<4; r++)
      cst[c16][r] = c0[(size_t)(b0 + l4*4 + r)*HH + wv*32 + c16*16 + l15];

  for(int st=0; st<TT; st++){
    __syncthreads();                         // staging/gather visible
    // ---- phase A: gates GEMM (bf16x6 MFMA) ----
    f32x4 acc[8];
    #pragma unroll
    for(int ff=0; ff<8; ff++){
      acc[ff][0]=bias[ff]; acc[ff][1]=bias[ff]; acc[ff][2]=bias[ff]; acc[ff][3]=bias[ff];
    }
    for(int kf=0; kf<NKF; kf++){
      const int ao = swA(l15, kf*64 + l4*16);
      const short8_t aH = *(const short8_t*)&AsH[ao];
      const short8_t aM = *(const short8_t*)&AsM[ao];
      const short8_t aL = *(const short8_t*)&AsL[ao];
      #pragma unroll
      for(int g=0; g<4; g++)
        #pragma unroll
        for(int c16=0; c16<2; c16++){
          const int f = g*16 + wv*2 + c16;
          const size_t wo = ((size_t)(f*NKF + kf)*64 + lane)*8;
          const short8_t bH = *(const short8_t*)(WfH + wo);
          const short8_t bM = *(const short8_t*)(WfM + wo);
          const short8_t bL = *(const short8_t*)(WfL + wo);
          MFMA_X6(aH,aM,aL,bH,bM,bL, acc[g*2+c16]);
        }
    }
    __syncthreads();                         // reads done before h-region writes
    // ---- cell epilogue: c in regs, h -> LDS fp32 + A h-region split3 ----
    #pragma unroll
    for(int c16=0; c16<2; c16++){
      const int j = wv*32 + c16*16 + l15;
      #pragma unroll
      for(int r=0; r<4; r++){
        const int row = l4*4 + r;
        const float iv = acc[0+c16][r];
        const float fv = acc[2+c16][r];
        const float gv = acc[4+c16][r];
        const float ov = acc[6+c16][r];
        const float cn = sigmoidf_(fv)*cst[c16][r] + sigmoidf_(iv)*tanhf(gv);
        const float hn = sigmoidf_(ov)*tanhf(cn);
        cst[c16][r] = cn;
        unsigned short sh, sm_, sl;
        bf16_split3(hn, sh, sm_, sl);
        const int hi = swA(row, (128 + j)*2);
        AsH[hi] = sh; AsM[hi] = sm_; AsL[hi] = sl;
        hs[row*264 + j] = hn;
      }
    }
    __syncthreads();
    // ---- phase B1: blend2 = h_new @ W2^T (VALU, K=256) ----
    {
      const int row = tid >> 5;
      const int n8  = (tid & 31) * 8;
      float a8[8];
      #pragma unroll
      for(int i=0;i<8;i++) a8[i] = 0.f;
      #pragma unroll 4
      for(int k=0; k<HH; k++){
        const float hv = hs[row*264 + k];
        const float4 w0 = *(const float4*)(W2t + (size_t)k*HH + n8);
        const float4 w1 = *(const float4*)(W2t + (size_t)k*HH + n8 + 4);
        a8[0]=fmaf(hv,w0.x,a8[0]); a8[1]=fmaf(hv,w0.y,a8[1]);
        a8[2]=fmaf(hv,w0.z,a8[2]); a8[3]=fmaf(hv,w0.w,a8[3]);
        a8[4]=fmaf(hv,w1.x,a8[4]); a8[5]=fmaf(hv,w1.y,a8[5]);
        a8[6]=fmaf(hv,w1.z,a8[6]); a8[7]=fmaf(hv,w1.w,a8[7]);
      }
      #pragma unroll
      for(int i=0;i<8;i++) b2s[row*264 + n8 + i] = a8[i];
    }
    __syncthreads();
    // ---- phase B2: scores, 16-lane groups, 4 t per wave-iter ----
    {
      const int g4 = lane >> 4, l16 = lane & 15;
      #pragma unroll
      for(int rr=0; rr<2; rr++){
        const int row = wv*2 + rr;
        const float* bl  = blend1 + ((size_t)(b0+row)*TT)*256;
        const float* b2p = &b2s[row*264];
        for(int tb=0; tb<25; tb++){
          const int t = tb*4 + g4;
          float p = 0.f;
          #pragma unroll
          for(int q=0; q<4; q++){
            const int k = l16*16 + q*4;
            const float4 x   = *(const float4*)(bl + (size_t)t*256 + k);
            const float4 b2v = *(const float4*)(b2p + k);
            const float4 vv4 = *(const float4*)(&vts[k]);
            p = fmaf(tanh_fast(x.x + b2v.x), vv4.x, p);
            p = fmaf(tanh_fast(x.y + b2v.y), vv4.y, p);
            p = fmaf(tanh_fast(x.z + b2v.z), vv4.z, p);
            p = fmaf(tanh_fast(x.w + b2v.w), vv4.w, p);
          }
          #pragma unroll
          for(int off=8; off>=1; off>>=1) p += __shfl_xor(p, off, 64);
          if(l16 == 0) sc[row][t] = p;
        }
      }
    }
    __syncthreads();
    // ---- phase B3: mask+argmax+softmax+out+gather (wave wv: rows 2wv,2wv+1) ----
    #pragma unroll
    for(int rr=0; rr<2; rr++){
      const int row  = wv*2 + rr;
      const int brow = b0 + row;
      const float m1 = selc[row][lane] ? NEGF : sc[row][lane];
      float bestv = m1; int besti = lane;
      const int t2 = lane + 64;
      float m2 = NEGF;
      if(t2 < TT){
        m2 = selc[row][t2] ? NEGF : sc[row][t2];
        if(m2 > bestv){ bestv = m2; besti = t2; }
      }
      #pragma unroll
      for(int off=32; off>=1; off>>=1){
        const float ov = __shfl_xor(bestv, off, 64);
        const int   oi = __shfl_xor(besti, off, 64);
        if(ov > bestv || (ov == bestv && oi < besti)){ bestv = ov; besti = oi; }
      }
      float e = __expf(m1 - bestv);
      if(t2 < TT) e += __expf(m2 - bestv);
      #pragma unroll
      for(int off=32; off>=1; off>>=1) e += __shfl_xor(e, off, 64);

      float* orow = outp + (size_t)brow*(TT*TT) + (size_t)st*TT;
      orow[lane] = fmaxf(__expf(m1 - bestv)/e, 1e-9f);
      if(t2 < TT) orow[t2] = fmaxf(__expf(m2 - bestv)/e, 1e-9f);
      if(lane == 0) selc[row][besti] = 1;
      // gather dec_in = targets[b, sel, :] -> A x-region split3
      #pragma unroll
      for(int dd=0; dd<2; dd++){
        const int d = lane + dd*64;
        const float xv = targets[((size_t)brow*TT + besti)*DD + d];
        unsigned short th, tm, tl;
        bf16_split3(xv, th, tm, tl);
        const int idx = swA(row, d*2);
        AsH[idx] = th; AsM[idx] = tm; AsL[idx] = tl;
      }
    }
  }
}

// In-place row transform: blend1_rows <- blend1_rows @ W1^T, bf16x6 MFMA. (verified r2)
__global__ __launch_bounds__(128) void k_blend1(
    float* __restrict__ blend1,
    const unsigned short* __restrict__ W1H, const unsigned short* __restrict__ W1M,
    const unsigned short* __restrict__ W1L)
{
  __shared__ alignas(16) unsigned short AsH[32*264], AsM[32*264], AsL[32*264];
  const int tid  = threadIdx.x;
  const int lane = tid & 63;
  const int wv   = tid >> 6;
  const int l15  = lane & 15;
  const int l4   = lane >> 4;
  const size_t r0 = (size_t)blockIdx.x * 32;

  #pragma unroll
  for(int it=0; it<16; it++){
    const int q  = it*128 + tid;
    const int r  = q >> 6;
    const int kq = (q & 63) << 2;
    const float4 v = *(const float4*)(blend1 + (r0+r)*256 + kq);
    unsigned short h0,m0_,l0,h1,m1_,l1,h2,m2_,l2,h3,m3_,l3;
    bf16_split3(v.x,h0,m0_,l0); bf16_split3(v.y,h1,m1_,l1);
    bf16_split3(v.z,h2,m2_,l2); bf16_split3(v.w,h3,m3_,l3);
    *(ushort4*)&AsH[r*264+kq] = make_ushort4(h0,h1,h2,h3);
    *(ushort4*)&AsM[r*264+kq] = make_ushort4(m0_,m1_,m2_,m3_);
    *(ushort4*)&AsL[r*264+kq] = make_ushort4(l0,l1,l2,l3);
  }
  __syncthreads();

  f32x4 acc[16];
  #pragma unroll
  for(int s=0;s<16;s++)
    #pragma unroll
    for(int e=0;e<4;e++) acc[s][e] = 0.f;

  const int rb = wv*16;
  for(int kt=0; kt<8; kt++){
    const int k0 = kt*32;
    const short8_t aH = *(const short8_t*)&AsH[(rb+l15)*264 + k0 + l4*8];
    const short8_t aM = *(const short8_t*)&AsM[(rb+l15)*264 + k0 + l4*8];
    const short8_t aL = *(const short8_t*)&AsL[(rb+l15)*264 + k0 + l4*8];
    #pragma unroll
    for(int fn=0; fn<16; fn++){
      const int n = fn*16 + l15;
      const short8_t bH = *(const short8_t*)(W1H + (size_t)n*256 + k0 + l4*8);
      const short8_t bM = *(const short8_t*)(W1M + (size_t)n*256 + k0 + l4*8);
      const short8_t bL = *(const short8_t*)(W1L + (size_t)n*256 + k0 + l4*8);
      MFMA_X6(aH,aM,aL, bH,bM,bL, acc[fn]);
    }
  }
  #pragma unroll
  for(int fn=0; fn<16; fn++)
    #pragma unroll
    for(int r=0; r<4; r++)
      blend1[(r0 + rb + l4*4 + r)*256 + fn*16 + l15] = acc[fn][r];
}

extern "C" void kernel_launch(void* const* d_in, const int* in_sizes, int n_in,
                              void* d_out, int out_size, void* d_ws, size_t ws_size,
                              hipStream_t stream)
{
  (void)in_sizes; (void)n_in; (void)out_size; (void)ws_size;
  const float* targets  = (const float*)d_in[0];
  const float* h0       = (const float*)d_in[1];
  const float* c0       = (const float*)d_in[2];
  const float* enc_w_ih = (const float*)d_in[3];
  const float* enc_w_hh = (const float*)d_in[4];
  const float* enc_b_ih = (const float*)d_in[5];
  const float* enc_b_hh = (const float*)d_in[6];
  const float* dec_w_ih = (const float*)d_in[7];
  const float* dec_w_hh = (const float*)d_in[8];
  const float* dec_b_ih = (const float*)d_in[9];
  const float* dec_b_hh = (const float*)d_in[10];
  const float* W1       = (const float*)d_in[11];
  const float* W2       = (const float*)d_in[12];
  const float* vt       = (const float*)d_in[13];
  float* outp = (float*)d_out;

  // ---- workspace carve-up (~221 MB) ----
  float* ws      = (float*)d_ws;
  float* blend1  = ws;                               // B*T*256 fp32 (210 MB)
  float* W2t     = blend1 + (size_t)BB*TT*256;       // 256*256
  char* pc = (char*)(W2t + 256*256);
  pc = (char*)(((uintptr_t)pc + 63) & ~(uintptr_t)63);
  unsigned short* q = (unsigned short*)pc;
  const size_t WFSZ = (size_t)1024*KTOT;             // 393216 elems
  unsigned short* eWfH = q; q += WFSZ;
  unsigned short* eWfM = q; q += WFSZ;
  unsigned short* eWfL = q; q += WFSZ;
  unsigned short* dWfH = q; q += WFSZ;
  unsigned short* dWfM = q; q += WFSZ;
  unsigned short* dWfL = q; q += WFSZ;
  unsigned short* w1H  = q; q += (size_t)256*256;
  unsigned short* w1M  = q; q += (size_t)256*256;
  unsigned short* w1L  = q; q += (size_t)256*256;

  // ---- prep ----
  const int packGrid = (1024*KTOT + 255)/256;
  k_packW<<<packGrid, 256, 0, stream>>>(enc_w_ih, enc_w_hh, eWfH, eWfM, eWfL);
  k_packW<<<packGrid, 256, 0, stream>>>(dec_w_ih, dec_w_hh, dWfH, dWfM, dWfL);
  k_split3<<<(256*256+255)/256, 256, 0, stream>>>(W1, w1H, w1M, w1L, 256*256);
  k_transpose256<<<256, 256, 0, stream>>>(W2, W2t);

  // ---- encoder: 128 blocks x 16 rows, 100 steps in-block ----
  k_encoder<<<NBLK, NTHR, 0, stream>>>(targets, eWfH, eWfM, eWfL,
                                       enc_b_ih, enc_b_hh, blend1);

  // ---- blend1 = enc_states @ W1^T, in place ----
  k_blend1<<<BB*TT/32, 128, 0, stream>>>(blend1, w1H, w1M, w1L);

  // ---- decoder: 128 blocks x 16 rows, 100 steps in-block ----
  k_decoder<<<NBLK, NTHR, 0, stream>>>(targets, dWfH, dWfM, dWfL,
                                       dec_b_ih, dec_b_hh, h0, c0,
                                       W2t, vt, blend1, outp);
}